// Round 1
// 505.601 us; speedup vs baseline: 1.0082x; 1.0082x over previous
//
#include <hip/hip_runtime.h>
#include <stdint.h>

// ---------------------------------------------------------------------------
// Types / helpers
// ---------------------------------------------------------------------------
typedef unsigned short u16;
typedef unsigned int   u32;
typedef short bf16x8 __attribute__((ext_vector_type(8)));   // 8 bf16 = 4 VGPRs
typedef float f32x4  __attribute__((ext_vector_type(4)));   // MFMA accumulator

__device__ __forceinline__ u16 f2bf(float f) {
    union { float f; u32 u; } v; v.f = f;
    u32 u = v.u;
    u32 r = (u + 0x7fffu + ((u >> 16) & 1u)) >> 16;   // RNE
    return (u16)r;
}
__device__ __forceinline__ float bf2f(u16 h) {
    union { u32 u; float f; } v; v.u = ((u32)h) << 16;
    return v.f;
}

// async global->LDS, 16 B per lane.  LDS dest must be wave-uniform base + lane*16.
__device__ __forceinline__ void gload_lds16(const void* g, void* l) {
    __builtin_amdgcn_global_load_lds(
        (__attribute__((address_space(1))) void*)g,
        (__attribute__((address_space(3))) void*)l,
        16, 0, 0);
}

// ---------------------------------------------------------------------------
// fp32 -> bf16 conversion, all three inputs in one launch (block-uniform split)
// ---------------------------------------------------------------------------
__global__ __launch_bounds__(256) void cvt_all(const float4* __restrict__ s1, uint2* __restrict__ d1,
                                               const float4* __restrict__ s2, uint2* __restrict__ d2,
                                               const float4* __restrict__ s3, uint2* __restrict__ d3) {
    const float4* s; uint2* d; int i;
    int b = blockIdx.x;
    if (b < 8192)        { s = s1; d = d1; i = b * 256 + threadIdx.x; }
    else if (b < 32768)  { s = s2; d = d2; i = (b - 8192) * 256 + threadIdx.x; }
    else                 { s = s3; d = d3; i = (b - 32768) * 256 + threadIdx.x; }
    float4 v = s[i];
    uint2 o;
    o.x = (u32)f2bf(v.x) | ((u32)f2bf(v.y) << 16);
    o.y = (u32)f2bf(v.z) | ((u32)f2bf(v.w) << 16);
    d[i] = o;
}

// ---------------------------------------------------------------------------
// NT GEMM: C[M,N] = A[M,K] * B[N,K]^T, A/B bf16 K-contiguous.  (unchanged)
// ---------------------------------------------------------------------------
template <typename OUT_T>
__global__ __launch_bounds__(256) void gemm_bt(const u16* __restrict__ A,
                                               const u16* __restrict__ B,
                                               OUT_T* __restrict__ C,
                                               int M, int N, int K) {
    __shared__ u16 As[2][128 * 32];
    __shared__ u16 Bs[2][128 * 32];

    const int tid  = threadIdx.x;
    const int lane = tid & 63;
    const int wv   = tid >> 6;
    const int row0 = blockIdx.y * 128;
    const int col0 = blockIdx.x * 128;

    const int wm = (wv >> 1) * 64;
    const int wn = (wv & 1) * 64;
    const int fr = lane & 15;
    const int fq = (lane >> 4) * 8;

    const int srow = lane >> 2;
    const int scol = (lane & 3) * 8;

    f32x4 acc[4][4];
#pragma unroll
    for (int i = 0; i < 4; ++i)
#pragma unroll
        for (int j = 0; j < 4; ++j) acc[i][j] = f32x4{0.f, 0.f, 0.f, 0.f};

    auto stage = [&](int buf, int k0) {
#pragma unroll
        for (int i = 0; i < 2; ++i) {
            const int chunk = wv * 2 + i;
            const int r     = chunk * 16 + srow;
            gload_lds16(A + (size_t)(row0 + r) * K + k0 + scol, &As[buf][r * 32 + scol]);
            gload_lds16(B + (size_t)(col0 + r) * K + k0 + scol, &Bs[buf][r * 32 + scol]);
        }
    };

    const int nk = K >> 5;
    stage(0, 0);

    for (int ki = 0; ki < nk; ++ki) {
        __syncthreads();
        if (ki + 1 < nk) stage((ki + 1) & 1, (ki + 1) << 5);

        const u16* as = As[ki & 1];
        const u16* bs = Bs[ki & 1];
        bf16x8 af[4], bf[4];
#pragma unroll
        for (int mt = 0; mt < 4; ++mt)
            af[mt] = *(const bf16x8*)&as[(wm + mt * 16 + fr) * 32 + fq];
#pragma unroll
        for (int nt = 0; nt < 4; ++nt)
            bf[nt] = *(const bf16x8*)&bs[(wn + nt * 16 + fr) * 32 + fq];
#pragma unroll
        for (int mt = 0; mt < 4; ++mt)
#pragma unroll
            for (int nt = 0; nt < 4; ++nt)
                acc[mt][nt] = __builtin_amdgcn_mfma_f32_16x16x32_bf16(
                    af[mt], bf[nt], acc[mt][nt], 0, 0, 0);
    }

    const int orow4 = (lane >> 4) * 4;
    const int ocol  = lane & 15;
#pragma unroll
    for (int mt = 0; mt < 4; ++mt)
#pragma unroll
        for (int nt = 0; nt < 4; ++nt)
#pragma unroll
            for (int r = 0; r < 4; ++r) {
                int mm = row0 + wm + mt * 16 + orow4 + r;
                int nn = col0 + wn + nt * 16 + ocol;
                float v = acc[mt][nt][r];
                if constexpr (sizeof(OUT_T) == 2)
                    C[(size_t)mm * N + nn] = (OUT_T)f2bf(v);
                else
                    C[(size_t)mm * N + nn] = (OUT_T)v;
            }
}

// ---------------------------------------------------------------------------
// prep_kv: blocks [0,4096) apply RoPE to K -> Kb(8,S,128);
//          blocks [4096,5120) transpose V -> Vt[8][128][2048].   (unchanged)
// ---------------------------------------------------------------------------
__global__ __launch_bounds__(256) void prep_kv(const u16* __restrict__ qkv,
                                               u16* __restrict__ Kb,
                                               u16* __restrict__ Vt) {
    if (blockIdx.x < 4096) {
        int id = blockIdx.x * 256 + threadIdx.x;
        int d  = id & 63;
        int t  = id >> 6;
        int kh = t & 7;
        int s  = t >> 3;
        const size_t rowbase = (size_t)s * 6144 + 4096;
        float inv = __expf(-(float)d * (9.210340371976184f / 64.0f));
        float ang = (float)s * inv;
        float cs, sn; __sincosf(ang, &sn, &cs);
        float x1 = bf2f(qkv[rowbase + kh * 128 + d]);
        float x2 = bf2f(qkv[rowbase + kh * 128 + d + 64]);
        size_t o = ((size_t)kh * 2048 + s) * 128 + d;
        Kb[o]      = f2bf(x1 * cs - x2 * sn);
        Kb[o + 64] = f2bf(x1 * sn + x2 * cs);
    } else {
        int id = (blockIdx.x - 4096) * 256 + threadIdx.x;
        int s8 = id & 255;
        int d  = (id >> 8) & 127;
        int vh = id >> 15;
        u16 tmp[8];
#pragma unroll
        for (int j = 0; j < 8; ++j)
            tmp[j] = qkv[(size_t)(s8 * 8 + j) * 6144 + 5120 + vh * 128 + d];
        *(uint4*)(Vt + ((size_t)vh * 128 + d) * 2048 + s8 * 8) = *(uint4*)tmp;
    }
}

// ---------------------------------------------------------------------------
// Softmax + in-register P transpose.
// Input sacc is the SWAPPED QK^T result: lane (m,quad) holds
//   P[k_local = nt*16+quad*4+r][q_local = w*16+m].
// Output af[kk2] is the PV A-fragment: lane (m,quad) holds
//   P[q = w*16+m][k = kk2*32 + quad*8 + (0..7)]  as bf16x8.
// Built with 8 cvt_pk + 4 permlane32_swap + 4 permlane16_swap (no LDS).
// Swap semantics (gfx950): permlane32_swap: vdst[32:63] <-> vsrc[0:31];
//                          permlane16_swap: vdst rows 1,3 <-> vsrc rows 0,2.
// ---------------------------------------------------------------------------
__device__ __forceinline__ void softmax_pack(f32x4 s[4], bool diag, int w, int m, int quad,
                                             float sl2e, float& lsum, bf16x8 af[2]) {
#pragma unroll
    for (int nt = 0; nt < 4; ++nt)
#pragma unroll
        for (int r = 0; r < 4; ++r) {
            float p = __builtin_amdgcn_exp2f(s[nt][r] * sl2e);
            if (diag && (nt * 16 + quad * 4 + r > w * 16 + m)) p = 0.f;
            s[nt][r] = p;
            lsum += p;
        }
#pragma unroll
    for (int kk2 = 0; kk2 < 2; ++kk2)
#pragma unroll
        for (int ws = 0; ws < 2; ++ws) {
            u32 a, b;
            asm("v_cvt_pk_bf16_f32 %0, %1, %2"
                : "=v"(a) : "v"(s[2 * kk2][2 * ws]), "v"(s[2 * kk2][2 * ws + 1]));
            asm("v_cvt_pk_bf16_f32 %0, %1, %2"
                : "=v"(b) : "v"(s[2 * kk2 + 1][2 * ws]), "v"(s[2 * kk2 + 1][2 * ws + 1]));
            asm("v_permlane32_swap_b32 %0, %1" : "+v"(a), "+v"(b));
            asm("v_permlane16_swap_b32 %0, %1" : "+v"(a), "+v"(b));
            ((u32*)&af[kk2])[ws]     = a;   // words j0 (ws=0) / j1 (ws=1)
            ((u32*)&af[kk2])[ws + 2] = b;   // words j2 (ws=0) / j3 (ws=1)
        }
}

// ---------------------------------------------------------------------------
// One (or two, fused) QK^T -> exp2 -> PV passes over a staged 64-row K/V tile.
// QK^T is computed SWAPPED: mfma(K_frag, Q_frag) -> C[k][q]; the register
// fragments serve unchanged since A/B fragment lane mappings are identical.
// When TWO, both q-tiles share every Ks/Vs fragment read and present two
// independent MFMA chains (ILP) -- P never touches LDS.
// ---------------------------------------------------------------------------
template <bool TWO>
__device__ __forceinline__ void attn_pass2(const bf16x8 qfA[4], const bf16x8 qfB[4],
                                           f32x4 accA[8], f32x4 accB[8],
                                           float& lA, float& lB,
                                           const u16* Ks, const u16* Vs,
                                           int w, int m, int quad,
                                           bool diagA, bool diagB, float sl2e) {
    f32x4 sA[4], sB[4];
#pragma unroll
    for (int nt = 0; nt < 4; ++nt) {
        sA[nt] = f32x4{0.f, 0.f, 0.f, 0.f};
        sB[nt] = f32x4{0.f, 0.f, 0.f, 0.f};
    }

    __builtin_amdgcn_s_setprio(1);
#pragma unroll
    for (int kk = 0; kk < 4; ++kk)
#pragma unroll
        for (int nt = 0; nt < 4; ++nt) {
            int pos = (kk * 4 + quad) ^ (m & 7);
            bf16x8 b = *(const bf16x8*)&Ks[(nt * 16 + m) * 128 + pos * 8];
            sB[nt] = __builtin_amdgcn_mfma_f32_16x16x32_bf16(b, qfB[kk], sB[nt], 0, 0, 0);
            if constexpr (TWO)
                sA[nt] = __builtin_amdgcn_mfma_f32_16x16x32_bf16(b, qfA[kk], sA[nt], 0, 0, 0);
        }
    __builtin_amdgcn_s_setprio(0);

    bf16x8 afA[2], afB[2];
    softmax_pack(sB, diagB, w, m, quad, sl2e, lB, afB);
    if constexpr (TWO) softmax_pack(sA, diagA, w, m, quad, sl2e, lA, afA);

    __builtin_amdgcn_s_setprio(1);
#pragma unroll
    for (int kk2 = 0; kk2 < 2; ++kk2)
#pragma unroll
        for (int nt = 0; nt < 8; ++nt) {
            int pos = (kk2 * 4 + quad) ^ (m & 7);
            bf16x8 b = *(const bf16x8*)&Vs[(nt * 16 + m) * 64 + pos * 8];
            accB[nt] = __builtin_amdgcn_mfma_f32_16x16x32_bf16(afB[kk2], b, accB[nt], 0, 0, 0);
            if constexpr (TWO)
                accA[nt] = __builtin_amdgcn_mfma_f32_16x16x32_bf16(afA[kk2], b, accA[nt], 0, 0, 0);
        }
    __builtin_amdgcn_s_setprio(0);
}

// ---------------------------------------------------------------------------
// MFMA flash attention.  Block p handles q-tiles {p, 31-p} for head blockIdx.y.
// Swapped QK^T + register P transpose: no P LDS buffer, merged A/B passes on
// shared tiles, setprio around MFMA clusters.  LDS = 64 KB/block (2 blocks/CU).
// ---------------------------------------------------------------------------
__global__ __launch_bounds__(256, 2) void attn_mfma(const u16* __restrict__ qkv,
                                                    const u16* __restrict__ Kb,
                                                    const u16* __restrict__ Vt,
                                                    u16* __restrict__ ctx) {
    __shared__ u16 Ks[2][64 * 128];
    __shared__ u16 Vs[2][128 * 64];

    const int tid  = threadIdx.x;
    const int lane = tid & 63;
    const int w    = tid >> 6;
    const int m    = lane & 15;
    const int quad = lane >> 4;
    const int h    = blockIdx.y;
    const int kh   = h >> 2;            // GQA groups = 4
    const int qtA  = blockIdx.x;        // 0..15
    const int qtB  = 31 - qtA;          // 16..31

    const u16* Ktile0 = Kb + (size_t)kh * 2048 * 128;
    const u16* Vtile0 = Vt + (size_t)kh * 128 * 2048;
    const float sl2e = 0.08838834764831845f * 1.4426950408889634f; // scale*log2(e)

    auto stage = [&](int buf, int kt) {
        const u16* Kt = Ktile0 + (size_t)kt * 64 * 128;
#pragma unroll
        for (int i = 0; i < 4; ++i) {
            int slot = i * 256 + tid;
            int row = slot >> 4, cp = slot & 15;
            int gc = cp ^ (row & 7);             // swizzle on global side
            gload_lds16(Kt + row * 128 + gc * 8, &Ks[buf][slot * 8]);
        }
        const u16* Vtt = Vtile0 + kt * 64;
#pragma unroll
        for (int i = 0; i < 4; ++i) {
            int slot = i * 256 + tid;
            int row = slot >> 3, cp = slot & 7;
            int gc = cp ^ (row & 7);
            gload_lds16(Vtt + (size_t)row * 2048 + gc * 8, &Vs[buf][slot * 8]);
        }
    };

    // ---- load Q rows for both q-tiles straight from qkv, RoPE in registers
    bf16x8 qa[4], qb[4];
#pragma unroll
    for (int which = 0; which < 2; ++which) {
        const int qt = which ? qtB : qtA;
        const int s  = qt * 64 + w * 16 + m;
        bf16x8 raw[4];
        const u16* qp = qkv + (size_t)s * 6144 + h * 128 + quad * 8;
#pragma unroll
        for (int kk = 0; kk < 4; ++kk)
            raw[kk] = *(const bf16x8*)(qp + kk * 32);
        bf16x8* dst = which ? qb : qa;
#pragma unroll
        for (int half = 0; half < 2; ++half)
#pragma unroll
            for (int j = 0; j < 8; ++j) {
                int d = half * 32 + quad * 8 + j;
                float inv = __expf(-(float)d * (9.210340371976184f / 64.0f));
                float ang = (float)s * inv;
                float cs, sn; __sincosf(ang, &sn, &cs);
                float x1 = bf2f(((const u16*)&raw[half])[j]);
                float x2 = bf2f(((const u16*)&raw[half + 2])[j]);
                ((u16*)&dst[half])[j]     = f2bf(x1 * cs - x2 * sn);
                ((u16*)&dst[half + 2])[j] = f2bf(x1 * sn + x2 * cs);
            }
    }

    f32x4 accA[8], accB[8];
#pragma unroll
    for (int i = 0; i < 8; ++i) { accA[i] = f32x4{0.f, 0.f, 0.f, 0.f}; accB[i] = f32x4{0.f, 0.f, 0.f, 0.f}; }
    float lA = 0.f, lB = 0.f;

    stage(0, 0);
    for (int kt = 0; kt <= qtB; ++kt) {
        __syncthreads();                       // drains *previous* prefetch only
        if (kt < qtB) stage((kt + 1) & 1, kt + 1);   // fly during this tile's math

        const u16* ks = Ks[kt & 1];
        const u16* vs = Vs[kt & 1];
        if (kt <= qtA)
            attn_pass2<true >(qa, qb, accA, accB, lA, lB, ks, vs, w, m, quad,
                              kt == qtA, false, sl2e);
        else
            attn_pass2<false>(qa, qb, accA, accB, lA, lB, ks, vs, w, m, quad,
                              false, kt == qtB, sl2e);
    }

    // ---- epilogues: lane holds l-partial for q-row (w*16+m) over its k's;
    // reduce across quads, then broadcast to the C-layout rows (quad*4+r).
#pragma unroll
    for (int which = 0; which < 2; ++which) {
        const int qt  = which ? qtB : qtA;
        f32x4*   acc  = which ? accB : accA;
        float    l    = which ? lB   : lA;
        l += __shfl_xor(l, 16);
        l += __shfl_xor(l, 32);
        float linv[4];
#pragma unroll
        for (int r = 0; r < 4; ++r)
            linv[r] = 1.f / __shfl(l, quad * 4 + r);
#pragma unroll
        for (int r = 0; r < 4; ++r) {
            size_t rowg = (size_t)(qt * 64 + w * 16 + quad * 4 + r);
#pragma unroll
            for (int nt = 0; nt < 8; ++nt)
                ctx[rowg * 4096 + h * 128 + nt * 16 + m] = f2bf(acc[nt][r] * linv[r]);
        }
    }
}

// ---------------------------------------------------------------------------
// Launcher
// ---------------------------------------------------------------------------
extern "C" void kernel_launch(void* const* d_in, const int* in_sizes, int n_in,
                              void* d_out, int out_size, void* d_ws, size_t ws_size,
                              hipStream_t stream) {
    const float* hs   = (const float*)d_in[0];   // (1,2048,4096)
    const float* wqkv = (const float*)d_in[1];   // (6144,4096)
    const float* wo   = (const float*)d_in[2];   // (4096,4096)
    float* out = (float*)d_out;                  // (1,2048,4096) fp32

    char* ws = (char*)d_ws;
    u16* hA  = (u16*)ws;  ws += (size_t)2048 * 4096 * 2;   // hidden bf16
    u16* wQ  = (u16*)ws;  ws += (size_t)6144 * 4096 * 2;   // Wqkv bf16
    u16* wO  = (u16*)ws;  ws += (size_t)4096 * 4096 * 2;   // Wo bf16
    u16* qkv = (u16*)ws;  ws += (size_t)2048 * 6144 * 2;   // qkv bf16
    u16* Kb  = (u16*)ws;  ws += (size_t)8 * 2048 * 128 * 2; // K, RoPE'd
    u16* Vt  = (u16*)ws;  ws += (size_t)8 * 128 * 2048 * 2; // V transposed
    u16* ctx = (u16*)ws;  ws += (size_t)2048 * 4096 * 2;   // attention output

    // all three fp32->bf16 conversions in one launch
    cvt_all<<<49152, 256, 0, stream>>>((const float4*)hs,   (uint2*)hA,
                                       (const float4*)wqkv, (uint2*)wQ,
                                       (const float4*)wo,   (uint2*)wO);

    // qkv = hidden @ Wqkv^T   (M=2048, N=6144, K=4096)
    gemm_bt<u16><<<dim3(48, 16), 256, 0, stream>>>(hA, wQ, qkv, 2048, 6144, 4096);

    // K RoPE + V transpose in one launch
    prep_kv<<<5120, 256, 0, stream>>>(qkv, Kb, Vt);

    // balanced, merged-pass, register-P flash attention
    attn_mfma<<<dim3(16, 32), 256, 0, stream>>>(qkv, Kb, Vt, ctx);

    // out = ctx @ Wo^T   (M=2048, N=4096, K=4096), fp32 out
    gemm_bt<float><<<dim3(32, 16), 256, 0, stream>>>(ctx, wO, out, 2048, 4096, 4096);
}